// Round 8
// baseline (894.001 us; speedup 1.0000x reference)
//
#include <hip/hip_runtime.h>
#include <hip/hip_bf16.h>

#define NG 4
#define ID 128
#define HD 128
#define TH 384      // 3*HD
#define NB 32
#define NT 1000
#define XW (NG*ID)  // 512
#define OW (NG*HD)  // 512
#define GSTRIDE (NG*TH)  // 1536 f16 per (b,t)

typedef _Float16 v8h __attribute__((ext_vector_type(8)));
typedef __attribute__((ext_vector_type(4))) float v4f;

__device__ __forceinline__ float sigm(float v) {
    return __fdividef(1.f, 1.f + __expf(-v));
}
__device__ __forceinline__ float tanh_(float v) {
    v = fminf(fmaxf(v, -15.f), 15.f);
    float e2 = __expf(2.f * v);
    return __fdividef(e2 - 1.f, e2 + 1.f);
}
__device__ __forceinline__ ushort f2h(float x) {
    _Float16 h = (_Float16)x;
    return __builtin_bit_cast(unsigned short, h);
}
__device__ __forceinline__ void gl2lds16(const void* g, void* l) {
    __builtin_amdgcn_global_load_lds(
        (const __attribute__((address_space(1))) unsigned int*)g,
        (__attribute__((address_space(3))) unsigned int*)l, 16, 0, 0);
}

// ---------------- Phase 1 (proven): gi = x @ w_ih^T + b_ih, f16 MFMA.
// grid (3, 250, 4), block 256.
__global__ __launch_bounds__(256) void gi_gemm_f16(
    const float* __restrict__ x,
    const float* __restrict__ w_ih,
    const float* __restrict__ b_ih,
    _Float16* __restrict__ gi)
{
    const int tid  = threadIdx.x;
    const int w    = tid >> 6, l = tid & 63;
    const int lr   = l & 15, lq = l >> 4;
    const int g    = blockIdx.z;
    const int n0   = blockIdx.x * 128 + (w >> 1) * 64;   // gate-col base
    const int row0 = blockIdx.y * 128 + (w & 1) * 64;    // (b*T+t) row base

    v4f acc[4][4];
    #pragma unroll
    for (int mi = 0; mi < 4; ++mi)
        #pragma unroll
        for (int ni = 0; ni < 4; ++ni)
            acc[mi][ni] = (v4f){0.f, 0.f, 0.f, 0.f};

    #pragma unroll
    for (int kf = 0; kf < 4; ++kf) {
        v8h bf[4], af[4];
        #pragma unroll
        for (int ni = 0; ni < 4; ++ni) {
            const float* p = &w_ih[(size_t)(g * TH + n0 + ni * 16 + lr) * ID + kf * 32 + lq * 8];
            float4 f0 = *reinterpret_cast<const float4*>(p);
            float4 f1 = *reinterpret_cast<const float4*>(p + 4);
            v8h v;
            v[0]=(_Float16)f0.x; v[1]=(_Float16)f0.y; v[2]=(_Float16)f0.z; v[3]=(_Float16)f0.w;
            v[4]=(_Float16)f1.x; v[5]=(_Float16)f1.y; v[6]=(_Float16)f1.z; v[7]=(_Float16)f1.w;
            bf[ni] = v;
        }
        #pragma unroll
        for (int mi = 0; mi < 4; ++mi) {
            const float* p = &x[(size_t)(row0 + mi * 16 + lr) * XW + g * ID + kf * 32 + lq * 8];
            float4 f0 = *reinterpret_cast<const float4*>(p);
            float4 f1 = *reinterpret_cast<const float4*>(p + 4);
            v8h v;
            v[0]=(_Float16)f0.x; v[1]=(_Float16)f0.y; v[2]=(_Float16)f0.z; v[3]=(_Float16)f0.w;
            v[4]=(_Float16)f1.x; v[5]=(_Float16)f1.y; v[6]=(_Float16)f1.z; v[7]=(_Float16)f1.w;
            af[mi] = v;
        }
        #pragma unroll
        for (int mi = 0; mi < 4; ++mi)
            #pragma unroll
            for (int ni = 0; ni < 4; ++ni)
                acc[mi][ni] = __builtin_amdgcn_mfma_f32_16x16x32_f16(
                    af[mi], bf[ni], acc[mi][ni], 0, 0, 0);
    }

    float bias[4];
    #pragma unroll
    for (int ni = 0; ni < 4; ++ni)
        bias[ni] = b_ih[g * TH + n0 + ni * 16 + lr];

    #pragma unroll
    for (int mi = 0; mi < 4; ++mi)
        #pragma unroll
        for (int ni = 0; ni < 4; ++ni) {
            const int n = n0 + ni * 16 + lr;
            #pragma unroll
            for (int r = 0; r < 4; ++r) {
                const int m = row0 + mi * 16 + lq * 4 + r;
                gi[((size_t)m * NG + g) * TH + n] = (_Float16)(acc[mi][ni][r] + bias[ni]);
            }
        }
}

// ---------------- Phase 2: MFMA recurrence, 4 waves (block 256), 2-wide gates.
// Wave w: gate rows j in [32w, 32w+32) for all 3 gates (6 m-tiles).
// gh redistribution via per-wave LDS scratch (intra-wave, no extra barrier).
// gi staged 8 steps/tile via global_load_lds. grid 32 (g, 4-batch chunk).
__global__ __launch_bounds__(256) void gru_rec6(
    const _Float16* __restrict__ gi,
    const float* __restrict__ w_hh,
    const float* __restrict__ b_hh,
    float* __restrict__ out)
{
    __shared__ __align__(16) ushort h_lds[2][16][152];     // ping-pong h, 304B rows
    __shared__ __align__(16) _Float16 tile[2][4 * 3080];   // 8t x 384 f16 per batch + pad
    __shared__ __align__(16) float gh_s[4][3][4][40];      // per-wave scratch

    const int tid = threadIdx.x;
    const int w = tid >> 6, l = tid & 63;
    const int lr = l & 15, lq = l >> 4;
    const int g  = blockIdx.x & 3;
    const int b0 = (blockIdx.x >> 2) * 4;

    // ---- w_hh A-frags (f16), once. a[i][s]: gate i, rows i*128+32w+16s+(0..15).
    v8h a[3][2][4];
    #pragma unroll
    for (int i = 0; i < 3; ++i)
        #pragma unroll
        for (int s = 0; s < 2; ++s) {
            const int mrow = i * 128 + 32 * w + 16 * s + lr;
            #pragma unroll
            for (int kf = 0; kf < 4; ++kf) {
                const float* p = &w_hh[(size_t)(g * TH + mrow) * HD + kf * 32 + lq * 8];
                float4 f0 = *reinterpret_cast<const float4*>(p);
                float4 f1 = *reinterpret_cast<const float4*>(p + 4);
                v8h v;
                v[0]=(_Float16)f0.x; v[1]=(_Float16)f0.y; v[2]=(_Float16)f0.z; v[3]=(_Float16)f0.w;
                v[4]=(_Float16)f1.x; v[5]=(_Float16)f1.y; v[6]=(_Float16)f1.z; v[7]=(_Float16)f1.w;
                a[i][s][kf] = v;
            }
        }

    // ---- gate identity: 2 elems/lane: batch nb = l&3, j = 32w + (l>>2)*2 (+0,1)
    const int nb  = l & 3;
    const int jp2 = (l >> 2) * 2;          // 0..30, even
    const int j   = 32 * w + jp2;
    const float2 bR2 = *reinterpret_cast<const float2*>(&b_hh[g * TH + j]);
    const float2 bZ2 = *reinterpret_cast<const float2*>(&b_hh[g * TH + 128 + j]);
    const float2 bN2 = *reinterpret_cast<const float2*>(&b_hh[g * TH + 256 + j]);
    float hp0 = 0.f, hp1 = 0.f;
    float* outp = out + (size_t)(b0 + nb) * NT * OW + g * HD + j;

    // ---- zero both h buffers
    for (int i = tid; i < 2 * 16 * 152 / 2; i += 256)
        reinterpret_cast<unsigned int*>(h_lds)[i] = 0u;

    // ---- DMA descriptors: 24 chunks/tile, 6 per wave; wave w stages batch w.
    const _Float16* gsrc[6];
    _Float16* ldst[2][6];
    #pragma unroll
    for (int i = 0; i < 6; ++i) {
        const int c = i;                       // 1KB chunk within batch region
        const int e = c * 512 + l * 8;         // f16 offset
        const int t_rel = e / 384, idx = e - t_rel * 384;
        gsrc[i] = gi + ((size_t)(b0 + w) * NT + t_rel) * GSTRIDE + g * TH + idx;
        ldst[0][i] = &tile[0][w * 3080 + c * 512];
        ldst[1][i] = &tile[1][w * 3080 + c * 512];
    }

    // ---- prologue: tile 0 -> buf 0
    #pragma unroll
    for (int i = 0; i < 6; ++i) gl2lds16(gsrc[i], ldst[0][i]);
    __syncthreads();

#define MFA(i, s, k, B) ac[i][s] = __builtin_amdgcn_mfma_f32_16x16x32_f16(a[i][s][k], B, ac[i][s], 0, 0, 0)

    for (int T = 0; T < NT / 8; ++T) {
        const int cbuf = T & 1;
        if (T < NT / 8 - 1) {
            const size_t go = (size_t)((T + 1) * 8) * GSTRIDE;
            #pragma unroll
            for (int i = 0; i < 6; ++i)
                gl2lds16(gsrc[i] + go, ldst[cbuf ^ 1][i]);
        }
        const _Float16* gl0 = &tile[cbuf][nb * 3080];
        float2 hv[8];
        #pragma unroll
        for (int k = 0; k < 8; ++k) {
            const char* hb = reinterpret_cast<const char*>(&h_lds[k & 1][0][0])
                             + lr * 304 + lq * 16;
            v8h bf0 = *reinterpret_cast<const v8h*>(hb);
            v8h bf1 = *reinterpret_cast<const v8h*>(hb + 64);
            v8h bf2 = *reinterpret_cast<const v8h*>(hb + 128);
            v8h bf3 = *reinterpret_cast<const v8h*>(hb + 192);
            v4f ac[3][2];
            #pragma unroll
            for (int i = 0; i < 3; ++i)
                #pragma unroll
                for (int s = 0; s < 2; ++s) ac[i][s] = (v4f){0.f,0.f,0.f,0.f};
            #pragma unroll
            for (int i = 0; i < 3; ++i) {
                MFA(i,0,0,bf0); MFA(i,1,0,bf0);
                MFA(i,0,1,bf1); MFA(i,1,1,bf1);
                MFA(i,0,2,bf2); MFA(i,1,2,bf2);
                MFA(i,0,3,bf3); MFA(i,1,3,bf3);
            }

            // ---- scatter (intra-wave): reg r of lane(lr<4,lq), tile(i,s)
            //      = gh[gate i][j_loc=16s+4lq+r][batch=lr]
            if (lr < 4) {
                #pragma unroll
                for (int i = 0; i < 3; ++i) {
                    *reinterpret_cast<v4f*>(&gh_s[w][i][lr][lq * 4])      = ac[i][0];
                    *reinterpret_cast<v4f*>(&gh_s[w][i][lr][16 + lq * 4]) = ac[i][1];
                }
            }
            // ---- gather 2-wide (same wave's scratch; lgkmcnt orders it)
            float2 Gr = *reinterpret_cast<const float2*>(&gh_s[w][0][nb][jp2]);
            float2 Gz = *reinterpret_cast<const float2*>(&gh_s[w][1][nb][jp2]);
            float2 Gn = *reinterpret_cast<const float2*>(&gh_s[w][2][nb][jp2]);

            const _Float16* gl = gl0 + k * 384;
            float iR0 = (float)gl[j],       iR1 = (float)gl[j + 1];
            float iZ0 = (float)gl[128 + j], iZ1 = (float)gl[129 + j];
            float iN0 = (float)gl[256 + j], iN1 = (float)gl[257 + j];

            float rr0 = sigm(iR0 + Gr.x + bR2.x);
            float rr1 = sigm(iR1 + Gr.y + bR2.y);
            float zz0 = sigm(iZ0 + Gz.x + bZ2.x);
            float zz1 = sigm(iZ1 + Gz.y + bZ2.y);
            float nn0 = tanh_(iN0 + rr0 * (Gn.x + bN2.x));
            float nn1 = tanh_(iN1 + rr1 * (Gn.y + bN2.y));
            float hn0 = fmaf(zz0, hp0 - nn0, nn0);
            float hn1 = fmaf(zz1, hp1 - nn1, nn1);
            hp0 = hn0; hp1 = hn1;
            hv[k] = make_float2(hn0, hn1);

            // ---- h -> LDS: lane owns (j, j+1) => direct u32 pack, no shfl
            unsigned int wv = (unsigned int)f2h(hn0) | ((unsigned int)f2h(hn1) << 16);
            *reinterpret_cast<unsigned int*>(&h_lds[(k + 1) & 1][nb][j]) = wv;
            __syncthreads();
        }
        // dump 8 outputs (float2), drain at next tile's first barrier
        const size_t ob = (size_t)(T * 8) * OW;
        #pragma unroll
        for (int k = 0; k < 8; ++k)
            *reinterpret_cast<float2*>(outp + ob + (size_t)k * OW) = hv[k];
    }
#undef MFA
}

extern "C" void kernel_launch(void* const* d_in, const int* in_sizes, int n_in,
                              void* d_out, int out_size, void* d_ws, size_t ws_size,
                              hipStream_t stream) {
    const float* x    = (const float*)d_in[0];
    const float* w_ih = (const float*)d_in[1];
    const float* w_hh = (const float*)d_in[2];
    const float* b_ih = (const float*)d_in[3];
    const float* b_hh = (const float*)d_in[4];
    float* out = (float*)d_out;
    _Float16* gi = (_Float16*)d_ws;   // [B*T, G, 384] f16 = 98.3 MB

    dim3 g1(3, 250, NG);
    gi_gemm_f16<<<g1, 256, 0, stream>>>(x, w_ih, b_ih, gi);
    gru_rec6<<<NB * NG / 4, 256, 0, stream>>>(gi, w_hh, b_hh, out);
}